// Round 8
// baseline (139.435 us; speedup 1.0000x reference)
//
#include <hip/hip_runtime.h>

#define BATCH 16
#define HH 512
#define WW 512
#define RSLICE 4
#define NSLICE (HH / RSLICE)   // 128
#define NWG (BATCH * NSLICE)   // 2048 blocks (divisible by 8 XCDs)

static constexpr size_t PLANE = (size_t)HH * WW;
static constexpr size_t COLP_ELEMS = (size_t)BATCH * NSLICE * WW; // 1M floats (4 MB)
static constexpr size_t ROWS_ELEMS = (size_t)BATCH * HH;          // 8192 floats

__device__ __forceinline__ float lum3(float a, float b, float c) {
  return 0.299f * a + 0.587f * b + 0.114f * c;
}

// Kernel A: LDS-luminance, 4-row slices, batched loads, XCD swizzle.
// r3/r4/r5/r7 all pinned at ~33-36 us (~3.4 TB/s) -> latency/in-flight-bytes
// bound, not BW-bound. This round: (1) ALL 15 input loads issued before any
// consumer (static-index array -> registers), 240 B/lane in flight vs ~96;
// (2) bijective XCD swizzle so slice s and s+1 (which share the halo row)
// run on the same XCD -> halo is an L2 hit; (3) NT reverted (r7: neutral).
__global__ __launch_bounds__(256) void jbd_reduce(const float* __restrict__ ref,
                                                  const float* __restrict__ tgt,
                                                  float* __restrict__ colp,
                                                  float* __restrict__ rows) {
  const int t = threadIdx.x;          // 0..255
  const int lane = t & 63;
  const int wid = t >> 6;
  // XCD-aware swizzle: blocks with equal (orig&7) share an XCD (round-robin
  // dispatch); they get 256 consecutive logical ids = consecutive slices.
  const int logical = (blockIdx.x & 7) * (NWG / 8) + (blockIdx.x >> 3);
  const int slice = logical & (NSLICE - 1);
  const int b = logical >> 7;         // / NSLICE
  const int r0 = slice * RSLICE;
  __shared__ float Lr[RSLICE + 1][WW];   // ref luminance rows r0..r0+4
  __shared__ float Lt[RSLICE + 1][WW];   // tgt luminance
  __shared__ float rowpart[RSLICE][4];

  // ---- Pass 1: 15 independent float4 loads, all issued up front ----
  {
    const int g = t >> 7;             // 0 = ref, 1 = tgt
    const int u = t & 127;            // cols 4u..4u+3
    const float* base = (g ? tgt : ref) + (size_t)b * 3 * PLANE;
    float* L = g ? &Lt[0][0] : &Lr[0][0];
    float4 p[RSLICE + 1][3];          // fully unrolled -> static indices -> regs
#pragma unroll
    for (int k = 0; k <= RSLICE; ++k) {
      const size_t o = (size_t)min(r0 + k, HH - 1) * WW + 4 * u;
#pragma unroll
      for (int c = 0; c < 3; ++c)
        p[k][c] = *(const float4*)(base + o + c * PLANE);
    }
#pragma unroll
    for (int k = 0; k <= RSLICE; ++k) {
      float4 l;
      l.x = lum3(p[k][0].x, p[k][1].x, p[k][2].x);
      l.y = lum3(p[k][0].y, p[k][1].y, p[k][2].y);
      l.z = lum3(p[k][0].z, p[k][1].z, p[k][2].z);
      l.w = lum3(p[k][0].w, p[k][1].w, p[k][2].w);
      *(float4*)&L[k * WW + 4 * u] = l;
    }
  }
  __syncthreads();

  // ---- Pass 2: diffs + reductions. Thread t owns cols 2t, 2t+1. ----
  float ca0 = 0.f, ca1 = 0.f;
  const int c0i = 2 * t;
  float lr0 = Lr[0][c0i], lr1 = Lr[0][c0i + 1];
  float lt0 = Lt[0][c0i], lt1 = Lt[0][c0i + 1];
#pragma unroll
  for (int i = 0; i < RSLICE; ++i) {
    // de_h row r0+i (neighbor col 2t+2; t==255 guarded; the read stays
    // in-bounds: Lr[i][512] aliases Lr[i+1][0])
    const float nlr = Lr[i][c0i + 2];
    const float nlt = Lt[i][c0i + 2];
    ca0 += fmaxf(fabsf(lt0 - lt1) - fabsf(lr0 - lr1), 0.f);
    if (t < 255)
      ca1 += fmaxf(fabsf(lt1 - nlt) - fabsf(lr1 - nlr), 0.f);
    // de_v row h = r0+i uses lum rows h, h+1
    const float xr0 = Lr[i + 1][c0i], xr1 = Lr[i + 1][c0i + 1];
    const float xt0 = Lt[i + 1][c0i], xt1 = Lt[i + 1][c0i + 1];
    float dv = 0.f;
    if (r0 + i < HH - 1) {               // block-uniform guard (h<=510 valid)
      dv = fmaxf(fabsf(xt0 - lt0) - fabsf(xr0 - lr0), 0.f)
         + fmaxf(fabsf(xt1 - lt1) - fabsf(xr1 - lr1), 0.f);
    }
    dv += __shfl_xor(dv, 1);
    dv += __shfl_xor(dv, 2);
    dv += __shfl_xor(dv, 4);
    dv += __shfl_xor(dv, 8);
    dv += __shfl_xor(dv, 16);
    dv += __shfl_xor(dv, 32);
    if (lane == 0) rowpart[i][wid] = dv;
    lr0 = xr0; lr1 = xr1; lt0 = xt0; lt1 = xt1;
  }
  __syncthreads();
  if (t < RSLICE) {
    const int h = r0 + t;
    if (h < HH - 1)                      // de_v rows are 0..510
      rows[(size_t)b * HH + h] =
          rowpart[t][0] + rowpart[t][1] + rowpart[t][2] + rowpart[t][3];
  }
  *(float2*)&colp[((size_t)b * NSLICE + slice) * WW + c0i] =
      make_float2(ca0, ca1);
}

// Kernel B: block per (direction, batch), 64 threads. Thread t owns the 8
// consecutive lines 8t..8t+7 (phase = j directly). float4 loads, per-phase
// butterfly reduce, then uniform 8-way argmax (strict > = first-index ties).
__global__ __launch_bounds__(64) void jbd_phase(const float* __restrict__ colp,
                                                const float* __restrict__ rows,
                                                int* __restrict__ results) {
  const int dir = blockIdx.x & 1;   // 0 = columns (de_h), 1 = rows (de_v)
  const int b = blockIdx.x >> 1;
  const int t = threadIdx.x;        // 0..63
  float c0 = 0.f, c1 = 0.f, c2 = 0.f, c3 = 0.f;
  float c4 = 0.f, c5 = 0.f, c6 = 0.f, c7 = 0.f;
  if (dir == 0) {
#pragma unroll 8
    for (int sl = 0; sl < NSLICE; ++sl) {
      const float* p = colp + ((size_t)b * NSLICE + sl) * WW + 8 * t;
      const float4 u = *(const float4*)p;
      const float4 v = *(const float4*)(p + 4);
      c0 += u.x; c1 += u.y; c2 += u.z; c3 += u.w;
      c4 += v.x; c5 += v.y; c6 += v.z; c7 += v.w;
    }
  } else {
    const float* p = rows + (size_t)b * HH + 8 * t;
    const float4 u = *(const float4*)p;
    const float4 v = *(const float4*)(p + 4);
    c0 = u.x; c1 = u.y; c2 = u.z; c3 = u.w;
    c4 = v.x; c5 = v.y; c6 = v.z; c7 = v.w;
  }
  if (t == 63) c7 = 0.f;            // line 511 does not exist (511 lines)
  float ps[8] = {c0, c1, c2, c3, c4, c5, c6, c7};
  float tot = 0.f;
#pragma unroll
  for (int p = 0; p < 8; ++p) {
    float v = ps[p];
    v += __shfl_xor(v, 1);
    v += __shfl_xor(v, 2);
    v += __shfl_xor(v, 4);
    v += __shfl_xor(v, 8);
    v += __shfl_xor(v, 16);
    v += __shfl_xor(v, 32);
    v *= (1.0f / 512.0f);           // line-mean divisor (H resp. W = 512)
    ps[p] = v;
    tot += v;
  }
  float best = -1.f;
  int bk = 0;
#pragma unroll
  for (int p = 0; p < 8; ++p) {
    const float cnt = (p == 7) ? 63.f : 64.f;  // phases 0..6 -> 64 lines, 7 -> 63
    const float a_k = ps[p] / cnt;
    const float bg = (tot - ps[p]) / (511.f - cnt);
    const float r = a_k / (bg + 1e-8f);
    if (r > best) { best = r; bk = p; }
  }
  if (t == 0) {
    results[4 * b + 2 * dir] = bk;
    results[4 * b + 2 * dir + 1] = (best > (float)(1.0 / 0.35)) ? 1 : 0;
  }
}

// Kernel C: broadcast per-batch decisions to the (B,1,H,W) mask, float4 stores.
__global__ __launch_bounds__(256) void jbd_write(const int* __restrict__ results,
                                                 float* __restrict__ out) {
  const int idx = blockIdx.x * 256 + threadIdx.x;  // float4 index
  const int b = idx >> 16;          // 512*128 float4 per batch
  const int rem = idx & 65535;
  const int h = rem >> 7;
  const int wq = rem & 127;
  const int4 rs = ((const int4*)results)[b];  // {bk_h, blocked_h, bk_v, blocked_v}
  const bool rowm = (rs.w != 0) && ((h & 7) == rs.z) && (h < HH - 1);
  float4 o;
  float* po = (float*)&o;
  const int w0 = wq << 2;
#pragma unroll
  for (int j = 0; j < 4; ++j) {
    const int w = w0 + j;
    const bool colm = (rs.y != 0) && ((w & 7) == rs.x) && (w < WW - 1);
    po[j] = (rowm || colm) ? 1.0f : 0.0f;
  }
  ((float4*)out)[idx] = o;
}

extern "C" void kernel_launch(void* const* d_in, const int* in_sizes, int n_in,
                              void* d_out, int out_size, void* d_ws, size_t ws_size,
                              hipStream_t stream) {
  (void)in_sizes; (void)n_in; (void)out_size; (void)ws_size;
  const float* ref = (const float*)d_in[0];
  const float* tgt = (const float*)d_in[1];
  float* colp = (float*)d_ws;                 // [B][NSLICE][W]
  float* rows = colp + COLP_ELEMS;            // [B][H] (index 511 unused)
  int* results = (int*)(rows + ROWS_ELEMS);   // [B][4]
  jbd_reduce<<<NWG, 256, 0, stream>>>(ref, tgt, colp, rows);
  jbd_phase<<<2 * BATCH, 64, 0, stream>>>(colp, rows, results);
  jbd_write<<<(BATCH * HH * WW / 4) / 256, 256, 0, stream>>>(results, (float*)d_out);
}